// Round 4
// baseline (60.988 us; speedup 1.0000x reference)
//
#include <hip/hip_runtime.h>
#include <hip/hip_bf16.h>

#define LOG2E 1.4426950408889634f
#define LN2   0.6931471805599453f

constexpr int Bn = 64, Sn = 512, Hn = 1024, Ln = 9;
constexpr int RB = 16;            // rows per block == chunk length
constexpr int NK = 32;            // row-blocks (chunks) per batch

__device__ __forceinline__ float fexp2(float x) {
    float r; asm("v_exp_f32 %0, %1" : "=v"(r) : "v"(x)); return r;
}
__device__ __forceinline__ float flog2(float x) {
    float r; asm("v_log_f32 %0, %1" : "=v"(r) : "v"(x)); return r;
}
__device__ __forceinline__ float max9(const float* s) {
    return fmaxf(fmaxf(fmaxf(s[0], s[1]), fmaxf(s[2], s[3])),
                 fmaxf(fmaxf(s[4], s[5]), fmaxf(s[6], fmaxf(s[7], s[8]))));
}

// ============ Kernel A: fused emissions (16 rows) + chunk transfer matrix ============
// Grid 2048 = 64 batches x 32 row-blocks; 256 thr (4 waves x 4 rows).
// Emissions stay in LDS; only 9x9 log2-chunk matrices + labeled emissions hit global.
__global__ __launch_bounds__(256, 4) void emis_chunk_kernel(
    const float* __restrict__ hidden, const float* __restrict__ W,
    const float* __restrict__ bias,   const float* __restrict__ T,
    const int* __restrict__ labels,   const int* __restrict__ mask,
    float* __restrict__ Mbuf, float* __restrict__ eL,
    float* __restrict__ e0g,  float* __restrict__ out)
{
    __shared__ float red[4][64][37];              // transpose-reduce scratch
    __shared__ __align__(16) float e_s[RB][12];   // this block's 16x9 emissions
    __shared__ __align__(16) float E_lds[Ln][12]; // exp(T)
    __shared__ int sl_sh;

    const int tid = threadIdx.x, w = tid >> 6, lane = tid & 63;
    const int bid = blockIdx.x, b = bid >> 5, k = bid & 31;
    const int r0  = b * Sn + k * RB;              // global row base

    if (bid == 0 && tid == 0) out[0] = 0.f;       // init loss accumulator

    // ---- stream phase: each wave does 4 rows over 4 passes of 256 H-floats
    float acc[4][Ln];
    #pragma unroll
    for (int r = 0; r < 4; ++r)
        #pragma unroll
        for (int l = 0; l < Ln; ++l) acc[r][l] = 0.f;

    #pragma unroll 1
    for (int p = 0; p < 4; ++p) {
        const int h0 = p * 256 + lane * 4;
        float4 wv[Ln];
        #pragma unroll
        for (int l = 0; l < Ln; ++l)
            wv[l] = *(const float4*)(W + l * Hn + h0);
        #pragma unroll
        for (int r = 0; r < 4; ++r) {
            float4 h = *(const float4*)(hidden + (size_t)(r0 + w * 4 + r) * Hn + h0);
            #pragma unroll
            for (int l = 0; l < Ln; ++l) {
                acc[r][l] = fmaf(h.x, wv[l].x, acc[r][l]);
                acc[r][l] = fmaf(h.y, wv[l].y, acc[r][l]);
                acc[r][l] = fmaf(h.z, wv[l].z, acc[r][l]);
                acc[r][l] = fmaf(h.w, wv[l].w, acc[r][l]);
            }
        }
    }

    if (w == 1 && lane < Ln) {                    // E = exp(T), into LDS
        #pragma unroll
        for (int j = 0; j < Ln; ++j)
            E_lds[lane][j] = fexp2(T[lane * Ln + j] * LOG2E);
    }

    #pragma unroll
    for (int r = 0; r < 4; ++r)
        #pragma unroll
        for (int l = 0; l < Ln; ++l)
            red[w][lane][r * Ln + l] = acc[r][l];
    __syncthreads();

    // ---- reduce (lanes<36): emissions -> e_s, eL, e0g
    if (lane < 36) {
        float s0 = 0.f, s1 = 0.f, s2 = 0.f, s3 = 0.f;
        #pragma unroll 4
        for (int i = 0; i < 64; i += 4) {
            s0 += red[w][i + 0][lane];
            s1 += red[w][i + 1][lane];
            s2 += red[w][i + 2][lane];
            s3 += red[w][i + 3][lane];
        }
        const int rr = lane / 9, l = lane - rr * 9;
        const int tloc = w * 4 + rr;
        const float v = (s0 + s1) + (s2 + s3) + bias[l];
        e_s[tloc][l] = v;
        const int t = k * RB + tloc;
        if (l == labels[b * Sn + t]) eL[b * Sn + t] = v;
        if (k == 0 && tloc == 0) e0g[b * Ln + l] = v;
    }
    if (w == 2) {                                 // sequence length
        const int* mb = mask + b * Sn;
        int s = 0;
        #pragma unroll
        for (int r = 0; r < Sn / 64; ++r) s += mb[lane + r * 64];
        #pragma unroll
        for (int off = 32; off; off >>= 1) s += __shfl_xor(s, off);
        if (lane == 0) sl_sh = s;
    }
    __syncthreads();

    // ---- chunk tail: wave 0, 9 lanes, linear domain u <- (u*E) o exp2(e*log2e - 4)
    if (w == 0 && lane < Ln) {
        const int sl  = sl_sh;
        const int tb  = (k == 0) ? 1 : 0;                 // first local step index
        const int lim = min(RB, sl - k * RB);             // valid local rows
        const int nst = lim - tb;                         // factors in this chunk
        if (nst > 0) {
            const int i = lane;
            float4 q0 = *(float4*)&e_s[tb][0];
            float4 q1 = *(float4*)&e_s[tb][4];
            float  q8 = e_s[tb][8];
            float qn[Ln] = {
                fexp2(fmaf(q0.x, LOG2E, -4.f)), fexp2(fmaf(q0.y, LOG2E, -4.f)),
                fexp2(fmaf(q0.z, LOG2E, -4.f)), fexp2(fmaf(q0.w, LOG2E, -4.f)),
                fexp2(fmaf(q1.x, LOG2E, -4.f)), fexp2(fmaf(q1.y, LOG2E, -4.f)),
                fexp2(fmaf(q1.z, LOG2E, -4.f)), fexp2(fmaf(q1.w, LOG2E, -4.f)),
                fexp2(fmaf(q8,   LOG2E, -4.f)) };
            float u[Ln];
            {
                float4 a0 = *(float4*)&E_lds[i][0];
                float4 a1 = *(float4*)&E_lds[i][4];
                float  a8 = E_lds[i][8];
                u[0] = a0.x * qn[0]; u[1] = a0.y * qn[1];
                u[2] = a0.z * qn[2]; u[3] = a0.w * qn[3];
                u[4] = a1.x * qn[4]; u[5] = a1.y * qn[5];
                u[6] = a1.z * qn[6]; u[7] = a1.w * qn[7];
                u[8] = a8   * qn[8];
            }
            float extra = 0.f;
            for (int s = 1; s < nst; ++s) {
                q0 = *(float4*)&e_s[tb + s][0];
                q1 = *(float4*)&e_s[tb + s][4];
                q8 = e_s[tb + s][8];
                qn[0] = fexp2(fmaf(q0.x, LOG2E, -4.f));
                qn[1] = fexp2(fmaf(q0.y, LOG2E, -4.f));
                qn[2] = fexp2(fmaf(q0.z, LOG2E, -4.f));
                qn[3] = fexp2(fmaf(q0.w, LOG2E, -4.f));
                qn[4] = fexp2(fmaf(q1.x, LOG2E, -4.f));
                qn[5] = fexp2(fmaf(q1.y, LOG2E, -4.f));
                qn[6] = fexp2(fmaf(q1.z, LOG2E, -4.f));
                qn[7] = fexp2(fmaf(q1.w, LOG2E, -4.f));
                qn[8] = fexp2(fmaf(q8,   LOG2E, -4.f));
                float v[Ln];
                #pragma unroll
                for (int j = 0; j < Ln; ++j) v[j] = 0.f;
                #pragma unroll
                for (int kk = 0; kk < Ln; ++kk) {
                    float4 e0v = *(float4*)&E_lds[kk][0];
                    float4 e1v = *(float4*)&E_lds[kk][4];
                    float  e8  = E_lds[kk][8];
                    const float uk = u[kk];
                    v[0] = fmaf(uk, e0v.x, v[0]); v[1] = fmaf(uk, e0v.y, v[1]);
                    v[2] = fmaf(uk, e0v.z, v[2]); v[3] = fmaf(uk, e0v.w, v[3]);
                    v[4] = fmaf(uk, e1v.x, v[4]); v[5] = fmaf(uk, e1v.y, v[5]);
                    v[6] = fmaf(uk, e1v.z, v[6]); v[7] = fmaf(uk, e1v.w, v[7]);
                    v[8] = fmaf(uk, e8,   v[8]);
                }
                #pragma unroll
                for (int j = 0; j < Ln; ++j) u[j] = v[j] * qn[j];
                if (s == 8) {                      // exponent-range insurance
                    float m  = max9(u);
                    float iv = 1.f / m;
                    #pragma unroll
                    for (int j = 0; j < Ln; ++j) u[j] *= iv;
                    extra = flog2(m);
                }
            }
            float* o = Mbuf + (size_t)bid * 81 + i * Ln;
            #pragma unroll
            for (int j = 0; j < Ln; ++j)
                o[j] = flog2(u[j]) + extra + 4.f * (float)nst;
        }
    }
}

// ============ Kernel B: combine chunks + score + loss ============
__global__ __launch_bounds__(256) void combine_kernel(
    const float* __restrict__ st, const float* __restrict__ et,
    const float* __restrict__ T,  const int* __restrict__ labels,
    const int* __restrict__ mask, const float* __restrict__ Mbuf,
    const float* __restrict__ eL, const float* __restrict__ e0g,
    float* __restrict__ out)
{
    __shared__ float part[4];
    const int b = blockIdx.x, tid = threadIdx.x;
    const int w = tid >> 6, lane = tid & 63;

    const int* mb = mask + b * Sn;
    int sl = 0;
    #pragma unroll
    for (int r = 0; r < Sn / 64; ++r) sl += mb[lane + r * 64];
    #pragma unroll
    for (int off = 32; off; off >>= 1) sl += __shfl_xor(sl, off);

    float logZ = 0.f;
    if (w == 0) {
        const int j9 = lane < Ln ? lane : Ln - 1;
        float al[Ln];
        #pragma unroll
        for (int j = 0; j < Ln; ++j) al[j] = (st[j] + e0g[b * Ln + j]) * LOG2E;
        const float* mcb = Mbuf + (size_t)(b * NK) * 81;
        const int klast = (sl - 1) >> 4;
        float col[Ln];
        #pragma unroll
        for (int i = 0; i < Ln; ++i) col[i] = mcb[i * Ln + j9];
        for (int k = 0; k <= klast; ++k) {
            float nc[Ln];
            if (k < klast) {
                const float* m2 = mcb + (size_t)(k + 1) * 81;
                #pragma unroll
                for (int i = 0; i < Ln; ++i) nc[i] = m2[i * Ln + j9];
            }
            float s[Ln];
            #pragma unroll
            for (int i = 0; i < Ln; ++i) s[i] = al[i] + col[i];
            float p = max9(s);
            float sum = fexp2(s[0] - p);
            #pragma unroll
            for (int i = 1; i < Ln; ++i) sum += fexp2(s[i] - p);
            float aj = p + flog2(sum);
            #pragma unroll
            for (int i = 0; i < Ln; ++i) al[i] = __shfl(aj, i);
            #pragma unroll
            for (int i = 0; i < Ln; ++i) col[i] = nc[i];
        }
        float z[Ln];
        #pragma unroll
        for (int j = 0; j < Ln; ++j) z[j] = al[j] + et[j] * LOG2E;
        float p = max9(z);
        float sum = fexp2(z[0] - p);
        #pragma unroll
        for (int j = 1; j < Ln; ++j) sum += fexp2(z[j] - p);
        logZ = (p + flog2(sum)) * LN2;
    } else {
        const int* lb = labels + b * Sn;
        float sc = 0.f;
        for (int t = (w - 1) * 64 + lane; t < sl; t += 192) {
            sc += eL[b * Sn + t];
            if (t >= 1) sc += T[lb[t - 1] * Ln + lb[t]];
        }
        #pragma unroll
        for (int off = 32; off; off >>= 1) sc += __shfl_xor(sc, off);
        if (w == 1 && lane == 0) sc += st[lb[0]] + et[lb[sl - 1]];
        if (lane == 0) part[w - 1] = sc;
    }
    __syncthreads();

    if (tid == 0) {
        float llh = part[0] + part[1] + part[2] - logZ;
        atomicAdd(out, llh * (-1.f / 64.f));
    }
}

extern "C" void kernel_launch(void* const* d_in, const int* in_sizes, int n_in,
                              void* d_out, int out_size, void* d_ws, size_t ws_size,
                              hipStream_t stream) {
    const float* hidden = (const float*)d_in[0];
    const float* W      = (const float*)d_in[1];
    const float* bias   = (const float*)d_in[2];
    const float* st     = (const float*)d_in[3];
    const float* et     = (const float*)d_in[4];
    const float* T      = (const float*)d_in[5];
    const int*   labels = (const int*)d_in[6];
    const int*   mask   = (const int*)d_in[7];

    float* Mbuf = (float*)d_ws;                       // 64*32*81  = 165888 floats
    float* eLp  = Mbuf + (size_t)Bn * NK * 81;        // 64*512    =  32768 floats
    float* e0g  = eLp + (size_t)Bn * Sn;              // 64*9      =    576 floats
    float* outp = (float*)d_out;

    emis_chunk_kernel<<<Bn * NK, 256, 0, stream>>>(hidden, W, bias, T, labels, mask,
                                                   Mbuf, eLp, e0g, outp);
    combine_kernel<<<Bn, 256, 0, stream>>>(st, et, T, labels, mask, Mbuf, eLp, e0g, outp);
}

// Round 5
// 43.764 us; speedup vs baseline: 1.3936x; 1.3936x over previous
//
#include <hip/hip_runtime.h>
#include <hip/hip_bf16.h>

#define LOG2E 1.4426950408889634f
#define LN2   0.6931471805599453f

constexpr int Bn = 64, Sn = 512, Hn = 1024, Ln = 9;
constexpr int CL = 24;                 // emission steps per chunk
constexpr int NC = 22;                 // ceil((Sn-1)/CL)

typedef __attribute__((ext_vector_type(8))) short short8v;
typedef __attribute__((ext_vector_type(4))) float f32x4;

__device__ __forceinline__ float fexp2(float x) {
    float r; asm("v_exp_f32 %0, %1" : "=v"(r) : "v"(x)); return r;
}
__device__ __forceinline__ float flog2(float x) {
    float r; asm("v_log_f32 %0, %1" : "=v"(r) : "v"(x)); return r;
}
__device__ __forceinline__ unsigned cvtpk(float lo, float hi) {
    unsigned r; asm("v_cvt_pk_bf16_f32 %0, %1, %2" : "=v"(r) : "v"(lo), "v"(hi)); return r;
}
__device__ __forceinline__ float max9(const float* s) {
    return fmaxf(fmaxf(fmaxf(s[0], s[1]), fmaxf(s[2], s[3])),
                 fmaxf(fmaxf(s[4], s[5]), fmaxf(s[6], fmaxf(s[7], s[8]))));
}

// ============ Kernel 1: emissions = hidden @ W^T + b via bf16 MFMA ============
// 512 blocks x 256 thr (4 waves x 16 rows = 64 rows/block). W packed once per
// block into LDS as per-lane MFMA B-fragments (32 KB); A converted on the fly.
// Fragment layout (16x16x32 bf16): A row = lane&15, k = 8*(lane>>4)+e;
// B col = lane&15, same k; D col = lane&15, row = 4*(lane>>4)+reg (m89/m91).
__global__ __launch_bounds__(256) void emis_kernel(
    const float* __restrict__ hidden, const float* __restrict__ W,
    const float* __restrict__ bias, float* __restrict__ emis,
    float* __restrict__ out0)
{
    __shared__ __align__(16) unsigned short wfrag[32][64][8];  // [kstep][lane][e]
    const int tid = threadIdx.x, lane = tid & 63, w = tid >> 6;

    if (blockIdx.x == 0 && tid == 0) out0[0] = 0.f;   // loss accumulator init

    // pack W (fp32 9x1024) -> bf16 B-fragments, zero-pad cols 9..15
    for (int f = tid; f < 32 * 64; f += 256) {
        const int s = f >> 6, l = f & 63;
        const int j = l & 15, k0 = s * 32 + ((l >> 4) << 3);
        uint4 pk = {0u, 0u, 0u, 0u};
        if (j < Ln) {
            float4 a = *(const float4*)(W + j * Hn + k0);
            float4 b = *(const float4*)(W + j * Hn + k0 + 4);
            pk.x = cvtpk(a.x, a.y); pk.y = cvtpk(a.z, a.w);
            pk.z = cvtpk(b.x, b.y); pk.w = cvtpk(b.z, b.w);
        }
        *(uint4*)&wfrag[s][l][0] = pk;
    }
    __syncthreads();

    const int row0 = blockIdx.x * 64 + w * 16;
    const float* hptr = hidden + (size_t)(row0 + (lane & 15)) * Hn + ((lane >> 4) << 3);

    f32x4 acc = {0.f, 0.f, 0.f, 0.f};
    #pragma unroll 4
    for (int s = 0; s < 32; ++s) {
        float4 a0 = *(const float4*)(hptr + s * 32);
        float4 a1 = *(const float4*)(hptr + s * 32 + 4);
        uint4 ap;
        ap.x = cvtpk(a0.x, a0.y); ap.y = cvtpk(a0.z, a0.w);
        ap.z = cvtpk(a1.x, a1.y); ap.w = cvtpk(a1.z, a1.w);
        short8v A  = *(short8v*)&ap;
        short8v Bv = *(const short8v*)&wfrag[s][lane][0];
        acc = __builtin_amdgcn_mfma_f32_16x16x32_bf16(A, Bv, acc, 0, 0, 0);
    }

    const int col = lane & 15;
    if (col < Ln) {
        const float bv = bias[col];
        #pragma unroll
        for (int r = 0; r < 4; ++r) {
            const int row = ((lane >> 4) << 2) + r;
            emis[(size_t)(row0 + row) * Ln + col] = acc[r] + bv;
        }
    }
}

// ============ Kernel 2: fused CRF (round-3 structure, reg-fixed + prefetch) ============
__global__ __launch_bounds__(256, 1) void crf_kernel(
    const float* __restrict__ emis, const float* __restrict__ st,
    const float* __restrict__ et,   const float* __restrict__ T,
    const int* __restrict__ labels, const int* __restrict__ mask,
    float* __restrict__ out)
{
    __shared__ __align__(16) float e_lds[Sn * Ln];   // raw emissions, 18432 B
    __shared__ float M_lds[NC][Ln][10];              // chunk matrices (log2 domain)
    __shared__ float part[4];
    __shared__ int   sl_sh;

    const int b    = blockIdx.x;
    const int tid  = threadIdx.x;
    const int w    = tid >> 6;
    const int lane = tid & 63;

    // P0: stage emissions + E=exp(T) (registers, launch_bounds(.,1) => no remat)
    {
        const float4* src = (const float4*)(emis + (size_t)b * Sn * Ln);
        float4* dst = (float4*)e_lds;
        for (int i = tid; i < (Sn * Ln) / 4; i += 256) dst[i] = src[i];
    }
    float E[Ln][Ln];
    #pragma unroll
    for (int k = 0; k < Ln; ++k)
        #pragma unroll
        for (int j = 0; j < Ln; ++j)
            E[k][j] = fexp2(T[k * Ln + j] * LOG2E);
    if (w == 3) {
        const int* mb = mask + b * Sn;
        int s = 0;
        #pragma unroll
        for (int r = 0; r < Sn / 64; ++r) s += mb[lane + r * 64];
        #pragma unroll
        for (int off = 32; off; off >>= 1) s += __shfl_xor(s, off);
        if (lane == 0) sl_sh = s;
    }
    __syncthreads();

    const int sl    = sl_sh;                    // >= 128
    const int nreal = (sl - 1 + CL - 1) / CL;

    // P1: chunk transfer matrices (9 lanes/unit, 7 units/wave, 22 units live)
    {
        const int ul = lane / 9;
        const int i  = lane - ul * 9;
        const int c  = w * 7 + ul;
        const int t0 = 1 + c * CL;
        if (ul < 7 && c < nreal) {
            const int nst = min(CL, sl - t0);
            float u[Ln];
            {
                const float* e0 = e_lds + t0 * Ln;
                #pragma unroll
                for (int j = 0; j < Ln; ++j)
                    u[j] = E[i][j] * fexp2(fmaf(e0[j], LOG2E, -4.f));
            }
            float extra = 0.f;
            for (int s = 1; s < nst; ++s) {
                // issue next emission row loads BEFORE the matvec (latency hide)
                const float* es = e_lds + (t0 + s) * Ln;
                float e2[Ln];
                #pragma unroll
                for (int j = 0; j < Ln; ++j) e2[j] = es[j];
                float v[Ln];
                #pragma unroll
                for (int j = 0; j < Ln; ++j) v[j] = 0.f;
                #pragma unroll
                for (int kk = 0; kk < Ln; ++kk) {
                    const float uk = u[kk];
                    #pragma unroll
                    for (int j = 0; j < Ln; ++j)
                        v[j] = fmaf(uk, E[kk][j], v[j]);
                }
                #pragma unroll
                for (int j = 0; j < Ln; ++j)
                    u[j] = v[j] * fexp2(fmaf(e2[j], LOG2E, -4.f));
                if (s == 12) {                  // exponent-range insurance
                    float m  = max9(u);
                    float iv = 1.f / m;
                    #pragma unroll
                    for (int j = 0; j < Ln; ++j) u[j] *= iv;
                    extra = flog2(m);
                }
            }
            #pragma unroll
            for (int j = 0; j < Ln; ++j)
                M_lds[c][i][j] = flog2(u[j]) + extra + 4.f * (float)nst;
        }
    }
    __syncthreads();

    // P2: wave 0 = combine; waves 1-3 = numerator score
    float logZ = 0.f;
    if (w == 0) {
        const int j9 = lane < Ln ? lane : Ln - 1;
        float al[Ln];
        #pragma unroll
        for (int j = 0; j < Ln; ++j) al[j] = (st[j] + e_lds[j]) * LOG2E;
        for (int c = 0; c < nreal; ++c) {
            float s[Ln];
            #pragma unroll
            for (int k = 0; k < Ln; ++k) s[k] = al[k] + M_lds[c][k][j9];
            float p = max9(s);
            float sum = fexp2(s[0] - p);
            #pragma unroll
            for (int k = 1; k < Ln; ++k) sum += fexp2(s[k] - p);
            float aj = p + flog2(sum);
            #pragma unroll
            for (int k = 0; k < Ln; ++k) al[k] = __shfl(aj, k);
        }
        float z[Ln];
        #pragma unroll
        for (int j = 0; j < Ln; ++j) z[j] = al[j] + et[j] * LOG2E;
        float p = max9(z);
        float sum = fexp2(z[0] - p);
        #pragma unroll
        for (int j = 1; j < Ln; ++j) sum += fexp2(z[j] - p);
        logZ = (p + flog2(sum)) * LN2;
    } else {
        const int* lb = labels + b * Sn;
        float sc = 0.f;
        for (int t = (w - 1) * 64 + lane; t < sl; t += 192) {
            int lt = lb[t];
            sc += e_lds[t * Ln + lt];
            if (t >= 1) sc += T[lb[t - 1] * Ln + lt];
        }
        #pragma unroll
        for (int off = 32; off; off >>= 1) sc += __shfl_xor(sc, off);
        if (w == 1 && lane == 0) sc += st[lb[0]] + et[lb[sl - 1]];
        if (lane == 0) part[w - 1] = sc;
    }
    __syncthreads();

    if (w == 0 && lane == 0) {
        float llh = part[0] + part[1] + part[2] - logZ;
        atomicAdd(out, llh * (-1.f / 64.f));
    }
}

extern "C" void kernel_launch(void* const* d_in, const int* in_sizes, int n_in,
                              void* d_out, int out_size, void* d_ws, size_t ws_size,
                              hipStream_t stream) {
    const float* hidden = (const float*)d_in[0];
    const float* W      = (const float*)d_in[1];
    const float* bias   = (const float*)d_in[2];
    const float* st     = (const float*)d_in[3];
    const float* et     = (const float*)d_in[4];
    const float* T      = (const float*)d_in[5];
    const int*   labels = (const int*)d_in[6];
    const int*   mask   = (const int*)d_in[7];

    float* emis = (float*)d_ws;                 // 32768 * 9 floats
    float* outp = (float*)d_out;

    emis_kernel<<<512, 256, 0, stream>>>(hidden, W, bias, emis, outp);
    crf_kernel<<<Bn, 256, 0, stream>>>(emis, st, et, T, labels, mask, outp);
}